// Round 1
// 405.800 us; speedup vs baseline: 1.0009x; 1.0009x over previous
//
#include <hip/hip_runtime.h>
#include <hip/hip_bf16.h>

typedef int i32x4 __attribute__((ext_vector_type(4)));

// async global->LDS, 16B per lane; LDS dest = wave-uniform base + lane*16
#define GLL16(g, l) __builtin_amdgcn_global_load_lds( \
    (const __attribute__((address_space(1))) void*)(g), \
    (__attribute__((address_space(3))) void*)(l), 16, 0, 0)

#define CFENCE() asm volatile("" ::: "memory")

// ---------------- abs-sum reduction (for per-tensor mean|w|) ----------------
__global__ __launch_bounds__(256) void abs_sum_kernel(const float* __restrict__ w, int n4,
                                                      double* __restrict__ out)
{
    double acc = 0.0;
    const float4* w4 = (const float4*)w;
    for (int i = blockIdx.x * blockDim.x + threadIdx.x; i < n4; i += gridDim.x * blockDim.x) {
        float4 v = w4[i];
        acc += (double)fabsf(v.x) + (double)fabsf(v.y) + (double)fabsf(v.z) + (double)fabsf(v.w);
    }
    for (int o = 32; o > 0; o >>= 1) acc += __shfl_down(acc, o, 64);
    __shared__ double part[4];
    int lane = threadIdx.x & 63, wv = threadIdx.x >> 6;
    if (lane == 0) part[wv] = acc;
    __syncthreads();
    if (threadIdx.x == 0) atomicAdd(out, part[0] + part[1] + part[2] + part[3]);
}

// ---------------- ternary weight quantization -> i8 {-1,0,1} ----------------
__global__ __launch_bounds__(256) void wquant_kernel(const float* __restrict__ w, int n4,
                                                     const double* __restrict__ sum, double inv_count,
                                                     char* __restrict__ out)
{
    float s = (float)(sum[0] * inv_count);
    s = fmaxf(s, 1e-5f);
    const float4* w4 = (const float4*)w;
    char4* o4 = (char4*)out;
    for (int i = blockIdx.x * blockDim.x + threadIdx.x; i < n4; i += gridDim.x * blockDim.x) {
        float4 v = w4[i];
        char4 c;
        c.x = (char)fminf(fmaxf(rintf(v.x / s), -1.0f), 1.0f);   // rintf = round-half-even
        c.y = (char)fminf(fmaxf(rintf(v.y / s), -1.0f), 1.0f);
        c.z = (char)fminf(fmaxf(rintf(v.z / s), -1.0f), 1.0f);
        c.w = (char)fminf(fmaxf(rintf(v.w / s), -1.0f), 1.0f);
        o4[i] = c;
    }
}

// ---------------- in-register H_16 butterfly helper ----------------
template<int NS>
__device__ __forceinline__ void hreg(float* v)
{
    #pragma unroll
    for (int h = 1; h < (1 << NS); h <<= 1)
        #pragma unroll
        for (int i = 0; i < 16; i++)
            if ((i & h) == 0) { float a = v[i], b = v[i + h]; v[i] = a + b; v[i + h] = a - b; }
}

// ---------------- FWHT + per-token absmax int8 quant (3-phase register FWHT) ----
template<int N, int TOKS>
__global__ __launch_bounds__(256) void fwht_quant_kernel(
    const float* __restrict__ in, long in_stride,
    char* __restrict__ outq, long out_stride,
    float* __restrict__ scales)
{
    constexpr int L = 256 / TOKS;          // threads per token (128 or 256)
    static_assert(N == 16 * L, "N must be 16*threads-per-token");
    __shared__ float sx[TOKS * N];
    __shared__ float red[4];

    const int tid = threadIdx.x;
    const int tk  = tid / L;
    const int lt  = tid % L;
    const long tok = (long)blockIdx.x * TOKS + tk;
    const float* row = in + tok * in_stride;
    float* s = sx + tk * N;

    float v[16];
    {
        const float4* r4 = (const float4*)(row + (size_t)lt * 16);
        float4 a[4];
        #pragma unroll
        for (int i = 0; i < 4; i++) a[i] = r4[i];
        #pragma unroll
        for (int i = 0; i < 4; i++) {
            v[4*i] = a[i].x; v[4*i+1] = a[i].y; v[4*i+2] = a[i].z; v[4*i+3] = a[i].w;
        }
    }
    hreg<4>(v);                            // h = 1,2,4,8
    #pragma unroll
    for (int i = 0; i < 4; i++)
        *(float4*)(s + lt * 16 + 4 * i) = make_float4(v[4*i], v[4*i+1], v[4*i+2], v[4*i+3]);
    __syncthreads();

    const int o = lt & 15, ss = lt >> 4;
    #pragma unroll
    for (int j = 0; j < 16; j++) v[j] = s[o + 256 * ss + 16 * j];
    hreg<(L == 256) ? 4 : 3>(v);           // h = 16..128 (L=256) or 16..64 (L=128)
    #pragma unroll
    for (int j = 0; j < 16; j++) s[o + 256 * ss + 16 * j] = v[j];
    __syncthreads();

    #pragma unroll
    for (int j = 0; j < 16; j++) v[j] = s[o + 16 * ss + L * j];
    hreg<4>(v);                            // top 4 stages

    const float rn = 1.0f / sqrtf((float)N);
    float m = 0.0f;
    #pragma unroll
    for (int j = 0; j < 16; j++) { v[j] *= rn; m = fmaxf(m, fabsf(v[j])); }
    for (int off = 32; off > 0; off >>= 1) m = fmaxf(m, __shfl_down(m, off, 64));
    if ((tid & 63) == 0) red[tid >> 6] = m;
    __syncthreads();
    float mm;
    if (TOKS == 1) mm = fmaxf(fmaxf(red[0], red[1]), fmaxf(red[2], red[3]));
    else           mm = fmaxf(red[2 * tk], red[2 * tk + 1]);
    mm = fmaxf(mm, 1e-5f);
    const float sc = 127.0f / mm;
    if (lt == 0) scales[tok] = sc;
    __syncthreads();                       // sx about to be reused as i8 buffer

    char* ct = (char*)sx + tk * N;
    #pragma unroll
    for (int j = 0; j < 16; j++) {
        float q = fminf(fmaxf(rintf(v[j] * sc), -127.0f), 127.0f);
        ct[o + 16 * ss + L * j] = (char)q;
    }
    __syncthreads();
    int4* dst = (int4*)(outq + tok * out_stride);
    dst[lt] = ((const int4*)ct)[lt];
}

// ---------------- i8 MFMA GEMM, 256x256 tile, 8 waves, 4-deep pipelined ----------
// C[t][o] = sum_k A[t][k]*B[o][k], fused dequant epilogue (+ optional relu^2).
// K-tile = 64 i8. Ring of 4 LDS buffers; tile t+3 staged while tile t computes;
// end-of-iteration wait is vmcnt(8) (tiles t+2,t+3 stay in flight across the
// barrier) -- never vmcnt(0) in the main loop.
// LDS XOR swizzle (seg' = seg ^ ((row>>1)&3)) applied as pre-swizzled global
// source + swizzled ds_read (global_load_lds dest must stay linear).
#define BM2 256
#define BN2 256
#define BK2 64

__global__ __launch_bounds__(512, 2) void gemm_bt_kernel(
    const char* __restrict__ A, int lda,
    const char* __restrict__ B, int ldb,
    float* __restrict__ C, int ldc,
    int K, int lognx,
    const float* __restrict__ sx,
    const double* __restrict__ wsum, double inv_count,
    int do_relu2)
{
    __shared__ __align__(16) char As[4][BM2 * BK2];   // 4 x 16 KB
    __shared__ __align__(16) char Bs[4][BN2 * BK2];   // 4 x 16 KB

    // XCD row-band swizzle (grid % 8 == 0 -> bijective)
    const int bid = blockIdx.x;
    const int xcd = bid & 7;
    const int n = bid >> 3;
    const int nper = gridDim.x >> 3;
    const int bx = n & ((1 << lognx) - 1);
    const int by = xcd * (nper >> lognx) + (n >> lognx);
    const int row0 = by * BM2;
    const int col0 = bx * BN2;

    const int tid = threadIdx.x;
    const int lane = tid & 63;
    const int w = tid >> 6;          // 8 waves
    const int wr = w >> 2;           // 0..1 : 128-row band
    const int wc = w & 3;            // 0..3 : 64-col band

    i32x4 acc[8][4] = {};

    // ---- staging addressing: linear LDS dest, swizzled global source ----
    // thread writes LDS row (w*16 + lane/4 [+128]), seg (lane&3);
    // it must contain global seg (lane&3) ^ ((row>>1)&3) = (lane&3)^((lane>>3)&3)
    const int srow = w * 16 + (lane >> 2);
    const int sseg = ((lane & 3) ^ ((lane >> 3) & 3)) << 4;
    const char* Ag0 = A + (size_t)(row0 + srow) * lda + sseg;
    const char* Ag1 = Ag0 + (size_t)128 * lda;
    const char* Bg0 = B + (size_t)(col0 + srow) * ldb + sseg;
    const char* Bg1 = Bg0 + (size_t)128 * ldb;
    const int wdst = w * 1024;       // wave chunk within one 8 KB GLL round

    // ---- fragment read addressing (swizzled) ----
    // frag row = band + i*16 + fr; k-seg fks = lane>>4; row bits 1..2 == fr bits 1..2
    const int fr = lane & 15;
    const int fks = lane >> 4;
    const int rsw = ((fks ^ ((fr >> 1) & 3)) << 4);
    const int aoff = (wr * 128 + fr) * BK2 + rsw;    // + i*1024
    const int boff = (wc * 64  + fr) * BK2 + rsw;    // + j*1024

    const int NT = K >> 6;           // 32 (GEMM1) / 64 (GEMM2)

    auto stage = [&](int tt) {
        const int sb = tt & 3;
        const int ko = tt * BK2;
        GLL16(Ag0 + ko, &As[sb][wdst]);
        GLL16(Ag1 + ko, &As[sb][wdst + 8192]);
        GLL16(Bg0 + ko, &Bs[sb][wdst]);
        GLL16(Bg1 + ko, &Bs[sb][wdst + 8192]);
    };
    auto compute = [&](int cb) {
        const char* as = As[cb];
        const char* bs = Bs[cb];
        i32x4 af[8], bf[4];
        #pragma unroll
        for (int i = 0; i < 8; ++i) af[i] = *(const i32x4*)(as + aoff + i * 1024);
        #pragma unroll
        for (int j = 0; j < 4; ++j) bf[j] = *(const i32x4*)(bs + boff + j * 1024);
        __builtin_amdgcn_s_setprio(1);
        #pragma unroll
        for (int i = 0; i < 8; ++i)
            #pragma unroll
            for (int j = 0; j < 4; ++j)
                acc[i][j] = __builtin_amdgcn_mfma_i32_16x16x64_i8(af[i], bf[j], acc[i][j], 0, 0, 0);
        __builtin_amdgcn_s_setprio(0);
    };

    // prologue: tiles 0,1,2 in flight; wait tile 0 (8 loads = tiles 1,2 remain)
    stage(0); stage(1); stage(2);
    asm volatile("s_waitcnt vmcnt(8)" ::: "memory");
    __builtin_amdgcn_s_barrier();
    CFENCE();

    int t = 0;
    for (; t < NT - 3; ++t) {
        stage(t + 3);                // writes buffer freed at the last barrier
        compute(t & 3);
        asm volatile("s_waitcnt vmcnt(8)" ::: "memory");   // tile t+1 landed
        __builtin_amdgcn_s_barrier();
        CFENCE();
    }
    compute(t & 3);                  // tile NT-3
    asm volatile("s_waitcnt vmcnt(4)" ::: "memory");       // tile NT-2 landed
    __builtin_amdgcn_s_barrier();
    CFENCE();
    ++t;
    compute(t & 3);                  // tile NT-2
    asm volatile("s_waitcnt vmcnt(0)" ::: "memory");       // tile NT-1 landed
    __builtin_amdgcn_s_barrier();
    CFENCE();
    ++t;
    compute(t & 3);                  // tile NT-1

    // epilogue: out = (float)acc * s_w / scale_x[row]; optional relu^2
    float sw = (float)(wsum[0] * inv_count);
    sw = fmaxf(sw, 1e-5f);
    const int qd = lane >> 4;
    #pragma unroll
    for (int i = 0; i < 8; ++i) {
        #pragma unroll
        for (int r = 0; r < 4; ++r) {
            int rowm = row0 + wr * 128 + i * 16 + qd * 4 + r;   // D row = (lane>>4)*4 + reg
            float esc = sw / sx[rowm];
            float* crow = C + (size_t)rowm * ldc + col0 + wc * 64;
            #pragma unroll
            for (int j = 0; j < 4; ++j) {
                float v = (float)acc[i][j][r] * esc;            // D col = lane&15
                if (do_relu2) { v = fmaxf(v, 0.0f); v = v * v; }
                crow[j * 16 + fr] = v;
            }
        }
    }
}

extern "C" void kernel_launch(void* const* d_in, const int* in_sizes, int n_in,
                              void* d_out, int out_size, void* d_ws, size_t ws_size,
                              hipStream_t stream)
{
    const float* X   = (const float*)d_in[0];   // (4,2048,2048) f32
    const float* Wup = (const float*)d_in[1];   // (4096,2048)   f32
    const float* Wdn = (const float*)d_in[2];   // (2048,4096)   f32
    float* out = (float*)d_out;                 // (4,2048,2048) f32

    const int Mtok = 8192, H = 2048, I = 4096;
    const int NW = H * I;                       // 8388608 = 2^23 weights per tensor

    // workspace layout
    char* ws = (char*)d_ws;
    double* sums = (double*)ws;                                  // 2 doubles
    float* sx1 = (float*)(ws + 1024);                            // 8192 f32
    float* sx2 = (float*)(ws + 1024 + 32768);                    // 8192 f32
    char* wqup = ws + (1 << 20);                                 // 8.4 MB (i8)
    char* wqdn = wqup + (size_t)NW;                              // 8.4 MB
    char* xq1  = wqdn + (size_t)NW;                              // 16.8 MB (i8)
    float* hbuf = (float*)(xq1 + (size_t)Mtok * H);              // 134 MB (h f32; xq2 i8 overlaid per-row)

    hipMemsetAsync(sums, 0, 16, stream);
    abs_sum_kernel<<<512, 256, 0, stream>>>(Wup, NW / 4, &sums[0]);
    abs_sum_kernel<<<512, 256, 0, stream>>>(Wdn, NW / 4, &sums[1]);
    const double invc = 1.0 / (double)NW;       // exactly 2^-23
    wquant_kernel<<<1024, 256, 0, stream>>>(Wup, NW / 4, &sums[0], invc, wqup);
    wquant_kernel<<<1024, 256, 0, stream>>>(Wdn, NW / 4, &sums[1], invc, wqdn);

    // stage 1: FWHT(H=2048) + quant, 2 tokens/block
    fwht_quant_kernel<2048, 2><<<Mtok / 2, 256, 0, stream>>>(X, H, xq1, H, sx1);
    // GEMM1 + relu^2 fused -> hbuf (f32, ld=I); grid 32x16 tiles -> 1-D swizzled, lognx=4
    gemm_bt_kernel<<<(I / BN2) * (Mtok / BM2), 512, 0, stream>>>(
        xq1, H, wqup, H, hbuf, I, H, 4, sx1, &sums[0], invc, 1);
    // stage 2: FWHT(I=4096) + quant; xq2 (i8) overlaid on hbuf rows (stride 4*I bytes)
    fwht_quant_kernel<4096, 1><<<Mtok, 256, 0, stream>>>(hbuf, I, (char*)hbuf, 4 * I, sx2);
    // GEMM2 -> out; grid 32x8 tiles -> 1-D swizzled, lognx=3
    gemm_bt_kernel<<<(H / BN2) * (Mtok / BM2), 512, 0, stream>>>(
        (const char*)hbuf, 4 * I, wqdn, I, out, H, I, 3, sx2, &sums[1], invc, 0);
}

// Round 2
// 399.751 us; speedup vs baseline: 1.0160x; 1.0151x over previous
//
#include <hip/hip_runtime.h>
#include <hip/hip_bf16.h>

typedef int i32x4 __attribute__((ext_vector_type(4)));

// async global->LDS, 16B per lane; LDS dest = wave-uniform base + lane*16
#define GLL16(g, l) __builtin_amdgcn_global_load_lds( \
    (const __attribute__((address_space(1))) void*)(g), \
    (__attribute__((address_space(3))) void*)(l), 16, 0, 0)

#define CFENCE() asm volatile("" ::: "memory")

// ---------------- abs-sum reduction (for per-tensor mean|w|) ----------------
__global__ __launch_bounds__(256) void abs_sum_kernel(const float* __restrict__ w, int n4,
                                                      double* __restrict__ out)
{
    double acc = 0.0;
    const float4* w4 = (const float4*)w;
    for (int i = blockIdx.x * blockDim.x + threadIdx.x; i < n4; i += gridDim.x * blockDim.x) {
        float4 v = w4[i];
        acc += (double)fabsf(v.x) + (double)fabsf(v.y) + (double)fabsf(v.z) + (double)fabsf(v.w);
    }
    for (int o = 32; o > 0; o >>= 1) acc += __shfl_down(acc, o, 64);
    __shared__ double part[4];
    int lane = threadIdx.x & 63, wv = threadIdx.x >> 6;
    if (lane == 0) part[wv] = acc;
    __syncthreads();
    if (threadIdx.x == 0) atomicAdd(out, part[0] + part[1] + part[2] + part[3]);
}

// ---------------- ternary weight quantization -> i8 {-1,0,1} ----------------
__global__ __launch_bounds__(256) void wquant_kernel(const float* __restrict__ w, int n4,
                                                     const double* __restrict__ sum, double inv_count,
                                                     char* __restrict__ out)
{
    float s = (float)(sum[0] * inv_count);
    s = fmaxf(s, 1e-5f);
    const float4* w4 = (const float4*)w;
    char4* o4 = (char4*)out;
    for (int i = blockIdx.x * blockDim.x + threadIdx.x; i < n4; i += gridDim.x * blockDim.x) {
        float4 v = w4[i];
        char4 c;
        c.x = (char)fminf(fmaxf(rintf(v.x / s), -1.0f), 1.0f);   // rintf = round-half-even
        c.y = (char)fminf(fmaxf(rintf(v.y / s), -1.0f), 1.0f);
        c.z = (char)fminf(fmaxf(rintf(v.z / s), -1.0f), 1.0f);
        c.w = (char)fminf(fmaxf(rintf(v.w / s), -1.0f), 1.0f);
        o4[i] = c;
    }
}

// ---------------- in-register H_16 butterfly helper ----------------
template<int NS>
__device__ __forceinline__ void hreg(float* v)
{
    #pragma unroll
    for (int h = 1; h < (1 << NS); h <<= 1)
        #pragma unroll
        for (int i = 0; i < 16; i++)
            if ((i & h) == 0) { float a = v[i], b = v[i + h]; v[i] = a + b; v[i + h] = a - b; }
}

// ---------------- FWHT + per-token absmax int8 quant (3-phase register FWHT) ----
template<int N, int TOKS>
__global__ __launch_bounds__(256) void fwht_quant_kernel(
    const float* __restrict__ in, long in_stride,
    char* __restrict__ outq, long out_stride,
    float* __restrict__ scales)
{
    constexpr int L = 256 / TOKS;          // threads per token (128 or 256)
    static_assert(N == 16 * L, "N must be 16*threads-per-token");
    __shared__ float sx[TOKS * N];
    __shared__ float red[4];

    const int tid = threadIdx.x;
    const int tk  = tid / L;
    const int lt  = tid % L;
    const long tok = (long)blockIdx.x * TOKS + tk;
    const float* row = in + tok * in_stride;
    float* s = sx + tk * N;

    float v[16];
    {
        const float4* r4 = (const float4*)(row + (size_t)lt * 16);
        float4 a[4];
        #pragma unroll
        for (int i = 0; i < 4; i++) a[i] = r4[i];
        #pragma unroll
        for (int i = 0; i < 4; i++) {
            v[4*i] = a[i].x; v[4*i+1] = a[i].y; v[4*i+2] = a[i].z; v[4*i+3] = a[i].w;
        }
    }
    hreg<4>(v);                            // h = 1,2,4,8
    #pragma unroll
    for (int i = 0; i < 4; i++)
        *(float4*)(s + lt * 16 + 4 * i) = make_float4(v[4*i], v[4*i+1], v[4*i+2], v[4*i+3]);
    __syncthreads();

    const int o = lt & 15, ss = lt >> 4;
    #pragma unroll
    for (int j = 0; j < 16; j++) v[j] = s[o + 256 * ss + 16 * j];
    hreg<(L == 256) ? 4 : 3>(v);           // h = 16..128 (L=256) or 16..64 (L=128)
    #pragma unroll
    for (int j = 0; j < 16; j++) s[o + 256 * ss + 16 * j] = v[j];
    __syncthreads();

    #pragma unroll
    for (int j = 0; j < 16; j++) v[j] = s[o + 16 * ss + L * j];
    hreg<4>(v);                            // top 4 stages

    const float rn = 1.0f / sqrtf((float)N);
    float m = 0.0f;
    #pragma unroll
    for (int j = 0; j < 16; j++) { v[j] *= rn; m = fmaxf(m, fabsf(v[j])); }
    for (int off = 32; off > 0; off >>= 1) m = fmaxf(m, __shfl_down(m, off, 64));
    if ((tid & 63) == 0) red[tid >> 6] = m;
    __syncthreads();
    float mm;
    if (TOKS == 1) mm = fmaxf(fmaxf(red[0], red[1]), fmaxf(red[2], red[3]));
    else           mm = fmaxf(red[2 * tk], red[2 * tk + 1]);
    mm = fmaxf(mm, 1e-5f);
    const float sc = 127.0f / mm;
    if (lt == 0) scales[tok] = sc;
    __syncthreads();                       // sx about to be reused as i8 buffer

    char* ct = (char*)sx + tk * N;
    #pragma unroll
    for (int j = 0; j < 16; j++) {
        float q = fminf(fmaxf(rintf(v[j] * sc), -127.0f), 127.0f);
        ct[o + 16 * ss + L * j] = (char)q;
    }
    __syncthreads();
    int4* dst = (int4*)(outq + tok * out_stride);
    dst[lt] = ((const int4*)ct)[lt];
}

// ---------------- i8 MFMA GEMM, 256x256 tile, 8 waves, 2-phase/K-tile pipeline ----
// C[t][o] = sum_k A[t][k]*B[o][k], fused dequant epilogue (+ optional relu^2).
// K-tile = 64 i8. Ring of 4 LDS buffers; tile t+3 staged (2 GLL rounds/phase)
// while tile t computes. Per phase: {ds_read subtile | GLL issue | barrier |
// setprio(1) 16xMFMA setprio(0) | barrier}; vmcnt(8) once per K-tile, never 0
// in the main loop (8 loads stay in flight across every barrier).
// LDS XOR swizzle: pre-swizzled global source + swizzled ds_read (dest linear).
#define BM2 256
#define BN2 256
#define BK2 64

__global__ __launch_bounds__(512, 2) void gemm_bt_kernel(
    const char* __restrict__ A, int lda,
    const char* __restrict__ B, int ldb,
    float* __restrict__ C, int ldc,
    int K, int lognx,
    const float* __restrict__ sx,
    const double* __restrict__ wsum, double inv_count,
    int do_relu2)
{
    __shared__ __align__(16) char As[4][BM2 * BK2];   // 4 x 16 KB
    __shared__ __align__(16) char Bs[4][BN2 * BK2];   // 4 x 16 KB

    // XCD row-band swizzle (grid % 8 == 0 -> bijective)
    const int bid = blockIdx.x;
    const int xcd = bid & 7;
    const int n = bid >> 3;
    const int nper = gridDim.x >> 3;
    const int bx = n & ((1 << lognx) - 1);
    const int by = xcd * (nper >> lognx) + (n >> lognx);
    const int row0 = by * BM2;
    const int col0 = bx * BN2;

    const int tid = threadIdx.x;
    const int lane = tid & 63;
    const int w = tid >> 6;          // 8 waves
    const int wr = w >> 2;           // 0..1 : 128-row band
    const int wc = w & 3;            // 0..3 : 64-col band

    i32x4 acc[8][4] = {};

    // ---- staging addressing: linear LDS dest, swizzled global source ----
    const int srow = w * 16 + (lane >> 2);
    const int sseg = ((lane & 3) ^ ((lane >> 3) & 3)) << 4;
    const char* Ag0 = A + (size_t)(row0 + srow) * lda + sseg;
    const char* Ag1 = Ag0 + (size_t)128 * lda;
    const char* Bg0 = B + (size_t)(col0 + srow) * ldb + sseg;
    const char* Bg1 = Bg0 + (size_t)128 * ldb;
    const int wdst = w * 1024;       // wave chunk within one 8 KB GLL round

    // ---- fragment read addressing (swizzled) ----
    const int fr = lane & 15;
    const int fks = lane >> 4;
    const int rsw = ((fks ^ ((fr >> 1) & 3)) << 4);
    const int aoff = (wr * 128 + fr) * BK2 + rsw;    // + i*1024
    const int boff = (wc * 64  + fr) * BK2 + rsw;    // + j*1024

    const int NT = K >> 6;           // 32 (GEMM1) / 64 (GEMM2)

    auto stageA = [&](int tt) {
        const int sb = tt & 3;
        const int ko = tt * BK2;
        GLL16(Ag0 + ko, &As[sb][wdst]);
        GLL16(Ag1 + ko, &As[sb][wdst + 8192]);
    };
    auto stageB = [&](int tt) {
        const int sb = tt & 3;
        const int ko = tt * BK2;
        GLL16(Bg0 + ko, &Bs[sb][wdst]);
        GLL16(Bg1 + ko, &Bs[sb][wdst + 8192]);
    };

    // one K-tile, 2 phases; staging of tile t+3 interleaved when STAGE
    auto tile_body = [&](int t, bool do_stage) __attribute__((always_inline)) {
        const int cb = t & 3;
        const char* as = As[cb];
        const char* bs = Bs[cb];
        i32x4 af[4], bf[4], af2[4];
        // ---- phase 0: rows 0-3 x cols 0-3 ----
        #pragma unroll
        for (int i = 0; i < 4; ++i) af[i] = *(const i32x4*)(as + aoff + i * 1024);
        #pragma unroll
        for (int j = 0; j < 4; ++j) bf[j] = *(const i32x4*)(bs + boff + j * 1024);
        if (do_stage) stageA(t + 3);
        __builtin_amdgcn_s_barrier();
        CFENCE();
        __builtin_amdgcn_s_setprio(1);
        #pragma unroll
        for (int i = 0; i < 4; ++i)
            #pragma unroll
            for (int j = 0; j < 4; ++j)
                acc[i][j] = __builtin_amdgcn_mfma_i32_16x16x64_i8(af[i], bf[j], acc[i][j], 0, 0, 0);
        __builtin_amdgcn_s_setprio(0);
        __builtin_amdgcn_s_barrier();
        CFENCE();
        // ---- phase 1: rows 4-7 x cols 0-3 (bf held in regs) ----
        #pragma unroll
        for (int i = 0; i < 4; ++i) af2[i] = *(const i32x4*)(as + aoff + (4 + i) * 1024);
        if (do_stage) stageB(t + 3);
        __builtin_amdgcn_s_barrier();
        CFENCE();
        __builtin_amdgcn_s_setprio(1);
        #pragma unroll
        for (int i = 0; i < 4; ++i)
            #pragma unroll
            for (int j = 0; j < 4; ++j)
                acc[4 + i][j] = __builtin_amdgcn_mfma_i32_16x16x64_i8(af2[i], bf[j], acc[4 + i][j], 0, 0, 0);
        __builtin_amdgcn_s_setprio(0);
    };

    // prologue: tiles 0,1,2 in flight (12 loads/wave); wait tile 0 (8 remain)
    stageA(0); stageB(0); stageA(1); stageB(1); stageA(2); stageB(2);
    asm volatile("s_waitcnt vmcnt(8)" ::: "memory");
    __builtin_amdgcn_s_barrier();
    CFENCE();

    for (int t = 0; t <= NT - 4; ++t) {
        tile_body(t, true);
        asm volatile("s_waitcnt vmcnt(8)" ::: "memory");   // tile t+1 landed
        __builtin_amdgcn_s_barrier();
        CFENCE();
    }
    tile_body(NT - 3, false);
    asm volatile("s_waitcnt vmcnt(4)" ::: "memory");       // tile NT-2 landed
    __builtin_amdgcn_s_barrier();
    CFENCE();
    tile_body(NT - 2, false);
    asm volatile("s_waitcnt vmcnt(0)" ::: "memory");       // tile NT-1 landed
    __builtin_amdgcn_s_barrier();
    CFENCE();
    tile_body(NT - 1, false);

    // epilogue: out = (float)acc * s_w / scale_x[row]; optional relu^2
    float sw = (float)(wsum[0] * inv_count);
    sw = fmaxf(sw, 1e-5f);
    const int qd = lane >> 4;
    #pragma unroll
    for (int i = 0; i < 8; ++i) {
        #pragma unroll
        for (int r = 0; r < 4; ++r) {
            int rowm = row0 + wr * 128 + i * 16 + qd * 4 + r;   // D row = (lane>>4)*4 + reg
            float esc = sw / sx[rowm];
            float* crow = C + (size_t)rowm * ldc + col0 + wc * 64;
            #pragma unroll
            for (int j = 0; j < 4; ++j) {
                float v = (float)acc[i][j][r] * esc;            // D col = lane&15
                if (do_relu2) { v = fmaxf(v, 0.0f); v = v * v; }
                crow[j * 16 + fr] = v;
            }
        }
    }
}

extern "C" void kernel_launch(void* const* d_in, const int* in_sizes, int n_in,
                              void* d_out, int out_size, void* d_ws, size_t ws_size,
                              hipStream_t stream)
{
    const float* X   = (const float*)d_in[0];   // (4,2048,2048) f32
    const float* Wup = (const float*)d_in[1];   // (4096,2048)   f32
    const float* Wdn = (const float*)d_in[2];   // (2048,4096)   f32
    float* out = (float*)d_out;                 // (4,2048,2048) f32

    const int Mtok = 8192, H = 2048, I = 4096;
    const int NW = H * I;                       // 8388608 = 2^23 weights per tensor

    // workspace layout
    char* ws = (char*)d_ws;
    double* sums = (double*)ws;                                  // 2 doubles
    float* sx1 = (float*)(ws + 1024);                            // 8192 f32
    float* sx2 = (float*)(ws + 1024 + 32768);                    // 8192 f32
    char* wqup = ws + (1 << 20);                                 // 8.4 MB (i8)
    char* wqdn = wqup + (size_t)NW;                              // 8.4 MB
    char* xq1  = wqdn + (size_t)NW;                              // 16.8 MB (i8)
    float* hbuf = (float*)(xq1 + (size_t)Mtok * H);              // 134 MB (h f32; xq2 i8 overlaid per-row)

    hipMemsetAsync(sums, 0, 16, stream);
    abs_sum_kernel<<<512, 256, 0, stream>>>(Wup, NW / 4, &sums[0]);
    abs_sum_kernel<<<512, 256, 0, stream>>>(Wdn, NW / 4, &sums[1]);
    const double invc = 1.0 / (double)NW;       // exactly 2^-23
    wquant_kernel<<<1024, 256, 0, stream>>>(Wup, NW / 4, &sums[0], invc, wqup);
    wquant_kernel<<<1024, 256, 0, stream>>>(Wdn, NW / 4, &sums[1], invc, wqdn);

    // stage 1: FWHT(H=2048) + quant, 2 tokens/block
    fwht_quant_kernel<2048, 2><<<Mtok / 2, 256, 0, stream>>>(X, H, xq1, H, sx1);
    // GEMM1 + relu^2 fused -> hbuf (f32, ld=I); grid 32x16 tiles -> 1-D swizzled, lognx=4
    gemm_bt_kernel<<<(I / BN2) * (Mtok / BM2), 512, 0, stream>>>(
        xq1, H, wqup, H, hbuf, I, H, 4, sx1, &sums[0], invc, 1);
    // stage 2: FWHT(I=4096) + quant; xq2 (i8) overlaid on hbuf rows (stride 4*I bytes)
    fwht_quant_kernel<4096, 1><<<Mtok, 256, 0, stream>>>(hbuf, I, (char*)hbuf, 4 * I, sx2);
    // GEMM2 -> out; grid 32x8 tiles -> 1-D swizzled, lognx=3
    gemm_bt_kernel<<<(H / BN2) * (Mtok / BM2), 512, 0, stream>>>(
        (const char*)hbuf, 4 * I, wqdn, I, out, H, I, 3, sx2, &sums[1], invc, 0);
}